// Round 20
// baseline (331.533 us; speedup 1.0000x reference)
//
#include <hip/hip_runtime.h>
#include <hip/hip_bf16.h>

#define BATCH 8
#define CIN   64
#define COUT  64
#define HH    128
#define WW    128
#define HW    (HH * WW)
#define OFFC  18
#define KK    9
#define SPX   68                  // staged columns: 64 + 2 halo each side
#define ROWB2 (SPX * 128)         // 8704 B per staged row
#define CPR   (SPX * 8)           // 544 16B-chunks per row

typedef __attribute__((ext_vector_type(8))) _Float16 half8;
typedef __attribute__((ext_vector_type(8))) unsigned short ushort8;
typedef __attribute__((ext_vector_type(4))) float f32x4;

__device__ __forceinline__ unsigned short f2hbits(float v) {
    _Float16 h = (_Float16)v;
    return __builtin_bit_cast(unsigned short, h);
}
__device__ __forceinline__ half8 splat8h(_Float16 h) {
    return (half8){h, h, h, h, h, h, h, h};
}

// ------- Kernel X: x (b,c,h,w) f32 -> xT (b,h,w,c) f16 -------
__global__ __launch_bounds__(256) void to_chlast_k(
    const float* __restrict__ x, unsigned short* __restrict__ xT)
{
    __shared__ unsigned short t[128 * 72];
    int blk = blockIdx.x;                    // ho*8 + b
    int b  = blk & 7;
    int ho = blk >> 3;
    int tid = threadIdx.x;

    const float* xr = x + (size_t)b * CIN * HW + ho * WW;
    for (int i = tid; i < 2048; i += 256) {
        int c = i >> 5, w4 = (i & 31) * 4;
        float4 v = *(const float4*)(xr + (size_t)c * HW + w4);
        t[(w4 + 0) * 72 + c] = f2hbits(v.x);
        t[(w4 + 1) * 72 + c] = f2hbits(v.y);
        t[(w4 + 2) * 72 + c] = f2hbits(v.z);
        t[(w4 + 3) * 72 + c] = f2hbits(v.w);
    }
    __syncthreads();

    unsigned short* orow = xT + (size_t)(b * HH + ho) * WW * 64;
    for (int j = tid; j < 1024; j += 256) {
        int w = j >> 3, c8 = (j & 7) * 8;
        *(ushort8*)(orow + w * 64 + c8) = *(const ushort8*)(t + w * 72 + c8);
    }
}

// ------- Kernel B (merged): w_deform -> wf frags; w_offset -> wfo frags (f16) -------
__global__ __launch_bounds__(256) void build_w_k(
    const float* __restrict__ wd, const float* __restrict__ wo,
    unsigned short* __restrict__ wf, unsigned short* __restrict__ wfo)
{
    int idx = blockIdx.x * 256 + threadIdx.x;
    if (idx < 36864) {                               // wf: o*576 + ck
        int ck = idx % 576;
        int o  = idx / 576;
        int c = ck & 63, k = ck >> 6;
        float v = wd[o * 576 + c * 9 + k];
        int kk = ck >> 5, nt = o >> 4;
        int lane = (o & 15) | (((ck >> 3) & 3) << 4);
        int j = ck & 7;
        wf[((kk * 4 + nt) * 64 + lane) * 8 + j] = f2hbits(v);
    } else if (idx < 36864 + 18432) {                // wfo: ov*576 + ck, N pad 18->32
        int i2 = idx - 36864;
        int ck = i2 % 576;
        int ov = i2 / 576;
        int c = ck & 63, tap = ck >> 6;
        float v = (ov < OFFC) ? wo[ov * 576 + c * 9 + tap] : 0.f;
        int kk = ck >> 5, nt = ov >> 4;
        int lane = (ov & 15) | (((ck >> 3) & 3) << 4);
        int j = ck & 7;
        wfo[((kk * 2 + nt) * 64 + lane) * 8 + j] = f2hbits(v);
    }
}

// ---------- Kernel C: 4-row strip blocks + rolling 8-row circular stage ----------
// R19 crash post-mortem: 8-row strips x 32 strips covered 256 rows on a 128-row
// image -> OOB stores. Fixed geometry: strip = 4 rows (2 row-pairs, 2 iters);
// grid = 32 strips x 2 wseg x 8 b = 512 blocks = exactly 2/CU, zero tail rounds.
// Iter 0: issue-early rows ho0+4/ho0+5 into regs, compute, write-late into the two
// provably-dead circular slots ((ho0+4)&7,(ho0+5)&7 outside live window
// (ho0-2..ho0+3)&7), one barrier. Staging per row-pair: 6 rows -> 4, half hidden.
__global__ __launch_bounds__(512, 4) void deform_fusedB_k(
    const unsigned short* __restrict__ xT,
    const half8* __restrict__ wfo,
    const half8* __restrict__ wf, float* __restrict__ out)
{
    __shared__ char  stage[8 * ROWB2];      // 69632 B
    __shared__ float offsL[8][16 * 20];     // 10240 B  (total 79872 -> 2 blocks/CU)

    int tid   = threadIdx.x;
    int blk   = blockIdx.x;                 // (strip*2+wseg)*8 + b
    int b     = blk & 7;
    int t2    = blk >> 3;
    int wseg  = t2 & 1;
    int strip = t2 >> 1;                    // 0..31, 4 rows each -> 128 rows
    int wo0   = wseg * 64;
    int col_lo = wo0 - 2;                   // staged cols col_lo .. col_lo+67

    const unsigned short* pT = xT + (size_t)b * HW * 64;

    int lane  = tid & 63;
    int wave  = tid >> 6;                   // 0..7
    int wl    = wave & 3;                   // px quarter
    int hrow  = wave >> 2;                  // 0/1: which row of the pair
    int prow  = lane & 15;
    int khalf = lane >> 4;
    int px    = wo0 + wl * 16 + prow;       // this lane's pixel (absolute)

    // ---- PROLOGUE: stage rows strip*4-2 .. strip*4+3 ----
    int ho0 = strip * 4;
    for (int c = tid; c < 6 * CPR; c += 512) {
        int r    = c / CPR;
        int cr   = c - r * CPR;
        int xs   = cr >> 3;
        int slot = cr & 7;
        int ar = ho0 - 2 + r, ac = col_lo + xs;
        if ((unsigned)ar < (unsigned)HH && (unsigned)ac < (unsigned)WW) {
            ushort8 v = *(const ushort8*)(pT + (((size_t)ar * WW + ac) << 6) + slot * 8);
            *(ushort8*)(stage + (ar & 7) * ROWB2 + xs * 128 + ((slot ^ (xs & 7)) << 4)) = v;
        }
    }
    __syncthreads();

    auto LRD = [&](int r, int xs, int slot) -> half8 {   // r = absolute_row & 7
        return *(const half8*)(stage + r * ROWB2 + xs * 128 + ((slot ^ (xs & 7)) << 4));
    };
    auto GRD = [&](int idx, int h) -> half8 {
        return *(const half8*)(pT + ((size_t)idx << 6) + (khalf << 3) + h * 32);
    };

    // this thread's 3 prefetch chunk descriptors (chunks tid, tid+512, tid+1024 of 2*CPR)
    int pc0 = tid, pc1 = tid + 512, pc2 = tid + 1024;    // pc2 valid iff pc2 < 1088
    int pr0 = pc0 / CPR, pcr0 = pc0 - pr0 * CPR;
    int pr1 = pc1 / CPR, pcr1 = pc1 - pr1 * CPR;
    int pr2 = pc2 / CPR, pcr2 = pc2 - pr2 * CPR;
    int pxs0 = pcr0 >> 3, psl0 = pcr0 & 7;
    int pxs1 = pcr1 >> 3, psl1 = pcr1 & 7;
    int pxs2 = pcr2 >> 3, psl2 = pcr2 & 7;
    int pac0 = col_lo + pxs0, pac1 = col_lo + pxs1, pac2 = col_lo + pxs2;

    #pragma unroll 1
    for (int it = 0; it < 2; ++it, ho0 += 2) {
        // ---- ISSUE-EARLY: loads for rows ho0+4, ho0+5 (dead slots this iter) ----
        ushort8 pf0 = {}, pf1 = {}, pf2 = {};
        bool pv0 = false, pv1 = false, pv2 = false;
        int  pw0 = 0, pw1 = 0, pw2 = 0;
        if (it == 0) {
            int ar0 = ho0 + 4 + pr0, ar1 = ho0 + 4 + pr1, ar2 = ho0 + 4 + pr2;
            pv0 = (unsigned)ar0 < (unsigned)HH && (unsigned)pac0 < (unsigned)WW;
            pv1 = (unsigned)ar1 < (unsigned)HH && (unsigned)pac1 < (unsigned)WW;
            pv2 = (pc2 < 2 * CPR) && (unsigned)ar2 < (unsigned)HH && (unsigned)pac2 < (unsigned)WW;
            if (pv0) pf0 = *(const ushort8*)(pT + (((size_t)ar0 * WW + pac0) << 6) + psl0 * 8);
            if (pv1) pf1 = *(const ushort8*)(pT + (((size_t)ar1 * WW + pac1) << 6) + psl1 * 8);
            if (pv2) pf2 = *(const ushort8*)(pT + (((size_t)ar2 * WW + pac2) << 6) + psl2 * 8);
            pw0 = ((ho0 + 4 + pr0) & 7) * ROWB2 + pxs0 * 128 + ((psl0 ^ (pxs0 & 7)) << 4);
            pw1 = ((ho0 + 4 + pr1) & 7) * ROWB2 + pxs1 * 128 + ((psl1 ^ (pxs1 & 7)) << 4);
            pw2 = ((ho0 + 4 + pr2) & 7) * ROWB2 + pxs2 * 128 + ((psl2 ^ (pxs2 & 7)) << 4);
        }

        int ho = ho0 + hrow;                // this wave's output row (< 128 by geometry)

        // ---- phase A: offsets conv via MFMA (f16) from the stage ----
        {
            f32x4 oa0 = {0.f,0.f,0.f,0.f}, oa1 = {0.f,0.f,0.f,0.f};
            #pragma unroll
            for (int kk = 0; kk < 18; ++kk) {
                int tap = kk >> 1;
                int y   = ho + tap / 3 - 1;        // in [ho0-1, ho0+2] subset of window
                int dx  = tap % 3 - 1;
                int slot = khalf + (kk & 1) * 4;
                half8 a0 = {0,0,0,0,0,0,0,0};
                int xw = px + dx;
                if ((unsigned)y < (unsigned)HH && (unsigned)xw < (unsigned)WW)
                    a0 = LRD(y & 7, xw - col_lo, slot);
                half8 b0 = wfo[(kk * 2 + 0) * 64 + lane];
                half8 b1 = wfo[(kk * 2 + 1) * 64 + lane];
                oa0 = __builtin_amdgcn_mfma_f32_16x16x32_f16(a0, b0, oa0, 0, 0, 0);
                oa1 = __builtin_amdgcn_mfma_f32_16x16x32_f16(a0, b1, oa1, 0, 0, 0);
            }
            int ocol = lane & 15;
            int pl0  = khalf * 4;
            #pragma unroll
            for (int r = 0; r < 4; ++r)
                offsL[wave][(pl0 + r) * 20 + ocol] = oa0[r];
            if (ocol < 2) {
                #pragma unroll
                for (int r = 0; r < 4; ++r)
                    offsL[wave][(pl0 + r) * 20 + 16 + ocol] = oa1[r];
            }
        }
        // no barrier: offsL slice is wave-private (lockstep + LDS order)

        // ---- tap loop: inline positions + LDS gather + packed-f16 interp + MFMA ----
        f32x4 acc0 = {0.f,0.f,0.f,0.f}, acc1 = {0.f,0.f,0.f,0.f};
        f32x4 acc2 = {0.f,0.f,0.f,0.f}, acc3 = {0.f,0.f,0.f,0.f};

        #pragma unroll
        for (int t = 0; t < 9; ++t) {
            half8 b00 = wf[((2 * t) * 4 + 0) * 64 + lane];
            half8 b01 = wf[((2 * t) * 4 + 1) * 64 + lane];
            half8 b02 = wf[((2 * t) * 4 + 2) * 64 + lane];
            half8 b03 = wf[((2 * t) * 4 + 3) * 64 + lane];
            half8 b10 = wf[((2 * t + 1) * 4 + 0) * 64 + lane];
            half8 b11 = wf[((2 * t + 1) * 4 + 1) * 64 + lane];
            half8 b12 = wf[((2 * t + 1) * 4 + 2) * 64 + lane];
            half8 b13 = wf[((2 * t + 1) * 4 + 3) * 64 + lane];

            float dy = offsL[wave][prow * 20 + 2 * t];
            float dx = offsL[wave][prow * 20 + 2 * t + 1];
            float yy = (float)(ho - 1 + t / 3) + dy;
            float xx = (float)(px - 1 + t % 3) + dx;
            float y0 = floorf(yy), x0 = floorf(xx);
            float wy1 = yy - y0, wx1 = xx - x0;
            float wy0 = 1.f - wy1, wx0 = 1.f - wx1;
            bool vv = (yy > -1.f) && (yy < (float)HH) && (xx > -1.f) && (xx < (float)WW);
            int y0i = (int)y0, x0i = (int)x0;
            bool iy0 = (unsigned)y0i < (unsigned)HH, iy1 = (unsigned)(y0i + 1) < (unsigned)HH;
            bool ix0 = (unsigned)x0i < (unsigned)WW, ix1 = (unsigned)(x0i + 1) < (unsigned)WW;
            float w00 = wy0 * wx0 * ((vv && iy0 && ix0) ? 1.f : 0.f);
            float w01 = wy0 * wx1 * ((vv && iy0 && ix1) ? 1.f : 0.f);
            float w10 = wy1 * wx0 * ((vv && iy1 && ix0) ? 1.f : 0.f);
            float w11 = wy1 * wx1 * ((vv && iy1 && ix1) ? 1.f : 0.f);
            int yc0 = min(max(y0i, 0), HH - 1), yc1 = min(max(y0i + 1, 0), HH - 1);
            int xc0 = min(max(x0i, 0), WW - 1), xc1 = min(max(x0i + 1, 0), WW - 1);

            int ry0 = yc0 - (ho0 - 2), ry1 = yc1 - (ho0 - 2);   // window-relative
            int xs0 = xc0 - col_lo,    xs1 = xc1 - col_lo;
            int r0 = yc0 & 7, r1 = yc1 & 7;
            int s0 = min(max(xs0, 0), SPX - 1), s1 = min(max(xs1, 0), SPX - 1);
            bool colOOT = ((unsigned)xs0 >= (unsigned)SPX) || ((unsigned)xs1 >= (unsigned)SPX);
            bool bad0 = ((unsigned)ry0 >= 6u) || colOOT;
            bool bad1 = ((unsigned)ry1 >= 6u) || colOOT;

            half8 C0a = LRD(r0, s0, khalf),     C0b = LRD(r0, s0, khalf + 4);
            half8 C1a = LRD(r0, s1, khalf),     C1b = LRD(r0, s1, khalf + 4);
            half8 C2a = LRD(r1, s0, khalf),     C2b = LRD(r1, s0, khalf + 4);
            half8 C3a = LRD(r1, s1, khalf),     C3b = LRD(r1, s1, khalf + 4);

            if (bad0) {                                      // rare: out of rolling window
                C0a = GRD(yc0 * WW + xc0, 0);  C0b = GRD(yc0 * WW + xc0, 1);
                C1a = GRD(yc0 * WW + xc1, 0);  C1b = GRD(yc0 * WW + xc1, 1);
            }
            if (bad1) {
                C2a = GRD(yc1 * WW + xc0, 0);  C2b = GRD(yc1 * WW + xc0, 1);
                C3a = GRD(yc1 * WW + xc1, 0);  C3b = GRD(yc1 * WW + xc1, 1);
            }

            half8 s00 = splat8h((_Float16)w00), s01 = splat8h((_Float16)w01);
            half8 s10 = splat8h((_Float16)w10), s11 = splat8h((_Float16)w11);
            half8 a0 = C0a * s00 + C1a * s01 + C2a * s10 + C3a * s11;
            half8 a1 = C0b * s00 + C1b * s01 + C2b * s10 + C3b * s11;

            acc0 = __builtin_amdgcn_mfma_f32_16x16x32_f16(a0, b00, acc0, 0, 0, 0);
            acc1 = __builtin_amdgcn_mfma_f32_16x16x32_f16(a0, b01, acc1, 0, 0, 0);
            acc2 = __builtin_amdgcn_mfma_f32_16x16x32_f16(a0, b02, acc2, 0, 0, 0);
            acc3 = __builtin_amdgcn_mfma_f32_16x16x32_f16(a0, b03, acc3, 0, 0, 0);
            acc0 = __builtin_amdgcn_mfma_f32_16x16x32_f16(a1, b10, acc0, 0, 0, 0);
            acc1 = __builtin_amdgcn_mfma_f32_16x16x32_f16(a1, b11, acc1, 0, 0, 0);
            acc2 = __builtin_amdgcn_mfma_f32_16x16x32_f16(a1, b12, acc2, 0, 0, 0);
            acc3 = __builtin_amdgcn_mfma_f32_16x16x32_f16(a1, b13, acc3, 0, 0, 0);
        }

        // ---- epilogue stores (nontemporal) ----
        {
            int ocol = lane & 15;
            int pixA = wo0 + wl * 16 + khalf * 4;
            float* ob = out + ((size_t)b * COUT) * HW + ho * WW;
            __builtin_nontemporal_store(acc0, (f32x4*)(ob + (size_t)(0 * 16 + ocol) * HW + pixA));
            __builtin_nontemporal_store(acc1, (f32x4*)(ob + (size_t)(1 * 16 + ocol) * HW + pixA));
            __builtin_nontemporal_store(acc2, (f32x4*)(ob + (size_t)(2 * 16 + ocol) * HW + pixA));
            __builtin_nontemporal_store(acc3, (f32x4*)(ob + (size_t)(3 * 16 + ocol) * HW + pixA));
        }

        // ---- WRITE-LATE: commit prefetched rows into dead slots, then barrier ----
        if (it == 0) {
            if (pv0) *(ushort8*)(stage + pw0) = pf0;
            if (pv1) *(ushort8*)(stage + pw1) = pf1;
            if (pv2) *(ushort8*)(stage + pw2) = pf2;
            __syncthreads();
        }
    }
}

extern "C" void kernel_launch(void* const* d_in, const int* in_sizes, int n_in,
                              void* d_out, int out_size, void* d_ws, size_t ws_size,
                              hipStream_t stream)
{
    const float* x    = (const float*)d_in[0];
    const float* woff = (const float*)d_in[1];
    const float* wdef = (const float*)d_in[2];
    float* out  = (float*)d_out;

    unsigned short* wfrag = (unsigned short*)d_ws;          // 73.7 KB
    unsigned short* wfo   = wfrag + 36864;                  // 36.9 KB
    unsigned short* xT    = wfo + 18432;                    // 16.8 MB

    hipLaunchKernelGGL(to_chlast_k, dim3(BATCH * HH), dim3(256), 0, stream,
                       x, xT);
    hipLaunchKernelGGL(build_w_k, dim3((36864 + 18432 + 255) / 256), dim3(256), 0, stream,
                       wdef, woff, wfrag, wfo);
    hipLaunchKernelGGL(deform_fusedB_k, dim3(32 * 2 * 8), dim3(512), 0, stream,
                       xT, (const half8*)wfo, (const half8*)wfrag, out);
}

// Round 21
// 54.870 us; speedup vs baseline: 6.0422x; 6.0422x over previous
//
#include <hip/hip_runtime.h>
#include <hip/hip_bf16.h>

#define BATCH 8
#define CIN   64
#define COUT  64
#define HH    128
#define WW    128
#define HW    (HH * WW)
#define OFFC  18
#define KK    9
#define NROWS 7
#define SPX   68                  // staged columns: 64 + 2 halo each side
#define ROWB2 (SPX * 128)         // 8704 B per staged row

typedef __attribute__((ext_vector_type(8))) _Float16 half8;
typedef __attribute__((ext_vector_type(8))) unsigned short ushort8;
typedef __attribute__((ext_vector_type(4))) float f32x4;

__device__ __forceinline__ unsigned short f2hbits(float v) {
    _Float16 h = (_Float16)v;
    return __builtin_bit_cast(unsigned short, h);
}
__device__ __forceinline__ half8 splat8(float f) {
    _Float16 h = (_Float16)f;
    return (half8){h, h, h, h, h, h, h, h};
}

// ------- Kernel X: x (b,c,h,w) f32 -> xT (b,h,w,c) f16 -------
__global__ __launch_bounds__(256) void to_chlast_k(
    const float* __restrict__ x, unsigned short* __restrict__ xT)
{
    __shared__ unsigned short t[128 * 72];
    int blk = blockIdx.x;                    // ho*8 + b
    int b  = blk & 7;
    int ho = blk >> 3;
    int tid = threadIdx.x;

    const float* xr = x + (size_t)b * CIN * HW + ho * WW;
    for (int i = tid; i < 2048; i += 256) {
        int c = i >> 5, w4 = (i & 31) * 4;
        float4 v = *(const float4*)(xr + (size_t)c * HW + w4);
        t[(w4 + 0) * 72 + c] = f2hbits(v.x);
        t[(w4 + 1) * 72 + c] = f2hbits(v.y);
        t[(w4 + 2) * 72 + c] = f2hbits(v.z);
        t[(w4 + 3) * 72 + c] = f2hbits(v.w);
    }
    __syncthreads();

    unsigned short* orow = xT + (size_t)(b * HH + ho) * WW * 64;
    for (int j = tid; j < 1024; j += 256) {
        int w = j >> 3, c8 = (j & 7) * 8;
        *(ushort8*)(orow + w * 64 + c8) = *(const ushort8*)(t + w * 72 + c8);
    }
}

// ------- Kernel B (merged): w_deform -> wf frags; w_offset -> wfo frags (f16) -------
__global__ __launch_bounds__(256) void build_w_k(
    const float* __restrict__ wd, const float* __restrict__ wo,
    unsigned short* __restrict__ wf, unsigned short* __restrict__ wfo)
{
    int idx = blockIdx.x * 256 + threadIdx.x;
    if (idx < 36864) {                               // wf: o*576 + ck
        int ck = idx % 576;
        int o  = idx / 576;
        int c = ck & 63, k = ck >> 6;
        float v = wd[o * 576 + c * 9 + k];
        int kk = ck >> 5, nt = o >> 4;
        int lane = (o & 15) | (((ck >> 3) & 3) << 4);
        int j = ck & 7;
        wf[((kk * 4 + nt) * 64 + lane) * 8 + j] = f2hbits(v);
    } else if (idx < 36864 + 18432) {                // wfo: ov*576 + ck, N pad 18->32
        int i2 = idx - 36864;
        int ck = i2 % 576;
        int ov = i2 / 576;
        int c = ck & 63, tap = ck >> 6;
        float v = (ov < OFFC) ? wo[ov * 576 + c * 9 + tap] : 0.f;
        int kk = ck >> 5, nt = ov >> 4;
        int lane = (ov & 15) | (((ck >> 3) & 3) << 4);
        int j = ck & 7;
        wfo[((kk * 2 + nt) * 64 + lane) * 8 + j] = f2hbits(v);
    }
}

// ---------- Kernel C: LDS-staged gather, 2-row x 64-px / 512-thr, 2 blocks/CU ----------
// R16 structure (session best, 54.9us): block = 2 rows x 64 px; stage = 7 rows x
// 68 cols (+-2 col halo) = 60.9KB + offsL 10KB = 71.2KB -> 2 blocks/CU -> 4
// waves/SIMD. Each of 8 waves owns 16 px (1 A-tile, 8 MFMAs/tap). Out-of-stage
// rows OR cols -> exec-masked global fallback of the SAME xT bytes (bit-identical,
// rare). Packed-f16 interp: zero conversions, result IS the MFMA fragment.
// R17-R20 lesson: record-dedup/reg-prefetch/rolling-stage all flat or negative
// (compiler re-sinks prefetches or spills); this is the verified optimum.
__global__ __launch_bounds__(512, 4) void deform_fused8_k(
    const unsigned short* __restrict__ xT,
    const half8* __restrict__ wfo,
    const half8* __restrict__ wf, float* __restrict__ out)
{
    __shared__ char  stage[NROWS * ROWB2];  // 60928 B
    __shared__ float offsL[8][16 * 20];     // 10240 B  (total 71168 B)

    int tid  = threadIdx.x;
    int blk  = blockIdx.x;                  // (rp*2+wseg)*8 + b
    int b    = blk & 7;
    int t2   = blk >> 3;
    int wseg = t2 & 1;
    int ho0  = (t2 >> 1) * 2;
    int row_lo = ho0 - 2;                   // staged rows row_lo .. row_lo+6
    int wo0  = wseg * 64;
    int col_lo = wo0 - 2;                   // staged cols col_lo .. col_lo+67

    const unsigned short* pT = xT + (size_t)b * HW * 64;

    int lane  = tid & 63;
    int wave  = tid >> 6;                   // 0..7
    int wl    = wave & 3;                   // px quarter
    int ho    = ho0 + (wave >> 2);          // this wave's output row
    int prow  = lane & 15;
    int khalf = lane >> 4;
    int px    = wo0 + wl * 16 + prow;       // this lane's pixel (absolute)

    // ---- STAGE: 7 rows x 68 cols of xT[b] -> swizzled LDS (512 threads) ----
    for (int c = tid; c < NROWS * SPX * 8; c += 512) {
        int r    = c / (SPX * 8);
        int rem  = c - r * (SPX * 8);
        int xs   = rem >> 3;
        int slot = rem & 7;
        int ar = row_lo + r, ac = col_lo + xs;
        if ((unsigned)ar < (unsigned)HH && (unsigned)ac < (unsigned)WW) {
            ushort8 v = *(const ushort8*)(pT + (((size_t)ar * WW + ac) << 6) + slot * 8);
            *(ushort8*)(stage + r * ROWB2 + xs * 128 + ((slot ^ (xs & 7)) << 4)) = v;
        }
    }
    __syncthreads();

    auto LRD = [&](int r, int xs, int slot) -> half8 {
        return *(const half8*)(stage + r * ROWB2 + xs * 128 + ((slot ^ (xs & 7)) << 4));
    };
    auto GRD = [&](int idx, int h) -> half8 {
        return *(const half8*)(pT + ((size_t)idx << 6) + (khalf << 3) + h * 32);
    };

    // ---- phase A: offsets conv via MFMA (f16) from the stage ----
    {
        f32x4 oa0 = {0.f,0.f,0.f,0.f}, oa1 = {0.f,0.f,0.f,0.f};
        #pragma unroll
        for (int kk = 0; kk < 18; ++kk) {
            int tap = kk >> 1;
            int y   = ho + tap / 3 - 1;
            int dx  = tap % 3 - 1;
            int slot = khalf + (kk & 1) * 4;
            half8 a0 = {0,0,0,0,0,0,0,0};
            int xw = px + dx;
            if ((unsigned)y < HH && (unsigned)xw < WW) {
                a0 = LRD(y - row_lo, xw - col_lo, slot);   // ry in [1,4], xs in [1,66]
            }
            half8 b0 = wfo[(kk * 2 + 0) * 64 + lane];
            half8 b1 = wfo[(kk * 2 + 1) * 64 + lane];
            oa0 = __builtin_amdgcn_mfma_f32_16x16x32_f16(a0, b0, oa0, 0, 0, 0);
            oa1 = __builtin_amdgcn_mfma_f32_16x16x32_f16(a0, b1, oa1, 0, 0, 0);
        }
        int ocol = lane & 15;
        int pl0  = khalf * 4;
        #pragma unroll
        for (int r = 0; r < 4; ++r)
            offsL[wave][(pl0 + r) * 20 + ocol] = oa0[r];
        if (ocol < 2) {
            #pragma unroll
            for (int r = 0; r < 4; ++r)
                offsL[wave][(pl0 + r) * 20 + 16 + ocol] = oa1[r];
        }
    }
    // no barrier: offsL slice is wave-private

    // ---- tap loop: inline positions + LDS gather + packed-f16 interp + MFMA ----
    f32x4 acc0 = {0.f,0.f,0.f,0.f}, acc1 = {0.f,0.f,0.f,0.f};
    f32x4 acc2 = {0.f,0.f,0.f,0.f}, acc3 = {0.f,0.f,0.f,0.f};

    #pragma unroll
    for (int t = 0; t < 9; ++t) {
        half8 b00 = wf[((2 * t) * 4 + 0) * 64 + lane];
        half8 b01 = wf[((2 * t) * 4 + 1) * 64 + lane];
        half8 b02 = wf[((2 * t) * 4 + 2) * 64 + lane];
        half8 b03 = wf[((2 * t) * 4 + 3) * 64 + lane];
        half8 b10 = wf[((2 * t + 1) * 4 + 0) * 64 + lane];
        half8 b11 = wf[((2 * t + 1) * 4 + 1) * 64 + lane];
        half8 b12 = wf[((2 * t + 1) * 4 + 2) * 64 + lane];
        half8 b13 = wf[((2 * t + 1) * 4 + 3) * 64 + lane];

        // ---------- positions ----------
        float dy = offsL[wave][prow * 20 + 2 * t];
        float dx = offsL[wave][prow * 20 + 2 * t + 1];
        float yy = (float)(ho - 1 + t / 3) + dy;
        float xx = (float)(px - 1 + t % 3) + dx;
        float y0 = floorf(yy), x0 = floorf(xx);
        float wy1 = yy - y0, wx1 = xx - x0;
        float wy0 = 1.f - wy1, wx0 = 1.f - wx1;
        bool vv = (yy > -1.f) && (yy < (float)HH) && (xx > -1.f) && (xx < (float)WW);
        int y0i = (int)y0, x0i = (int)x0;
        bool iy0 = (unsigned)y0i < HH, iy1 = (unsigned)(y0i + 1) < HH;
        bool ix0 = (unsigned)x0i < WW, ix1 = (unsigned)(x0i + 1) < WW;
        float w00 = wy0 * wx0 * ((vv && iy0 && ix0) ? 1.f : 0.f);
        float w01 = wy0 * wx1 * ((vv && iy0 && ix1) ? 1.f : 0.f);
        float w10 = wy1 * wx0 * ((vv && iy1 && ix0) ? 1.f : 0.f);
        float w11 = wy1 * wx1 * ((vv && iy1 && ix1) ? 1.f : 0.f);
        int yc0 = min(max(y0i, 0), HH - 1), yc1 = min(max(y0i + 1, 0), HH - 1);
        int xc0 = min(max(x0i, 0), WW - 1), xc1 = min(max(x0i + 1, 0), WW - 1);

        // ---------- stage coords + in-stage tests ----------
        int ry0 = yc0 - row_lo, ry1 = yc1 - row_lo;
        int xs0 = xc0 - col_lo, xs1 = xc1 - col_lo;
        int r0 = min(max(ry0, 0), NROWS - 1), r1 = min(max(ry1, 0), NROWS - 1);
        int s0 = min(max(xs0, 0), SPX - 1),   s1 = min(max(xs1, 0), SPX - 1);
        bool colOOT = ((unsigned)xs0 >= (unsigned)SPX) || ((unsigned)xs1 >= (unsigned)SPX);
        bool bad0 = ((unsigned)ry0 >= (unsigned)NROWS) || colOOT;
        bool bad1 = ((unsigned)ry1 >= (unsigned)NROWS) || colOOT;

        // ---------- LDS gathers (ds_read_b128) ----------
        half8 C0a = LRD(r0, s0, khalf),     C0b = LRD(r0, s0, khalf + 4);
        half8 C1a = LRD(r0, s1, khalf),     C1b = LRD(r0, s1, khalf + 4);
        half8 C2a = LRD(r1, s0, khalf),     C2b = LRD(r1, s0, khalf + 4);
        half8 C3a = LRD(r1, s1, khalf),     C3b = LRD(r1, s1, khalf + 4);

        // ---------- rare out-of-stage fallbacks (same bytes from global) ----------
        if (bad0) {
            C0a = GRD(yc0 * WW + xc0, 0);  C0b = GRD(yc0 * WW + xc0, 1);
            C1a = GRD(yc0 * WW + xc1, 0);  C1b = GRD(yc0 * WW + xc1, 1);
        }
        if (bad1) {
            C2a = GRD(yc1 * WW + xc0, 0);  C2b = GRD(yc1 * WW + xc0, 1);
            C3a = GRD(yc1 * WW + xc1, 0);  C3b = GRD(yc1 * WW + xc1, 1);
        }

        // ---------- packed-f16 interp: result IS the MFMA fragment ----------
        half8 s00 = splat8(w00), s01 = splat8(w01), s10 = splat8(w10), s11 = splat8(w11);
        half8 a0 = C0a * s00 + C1a * s01 + C2a * s10 + C3a * s11;
        half8 a1 = C0b * s00 + C1b * s01 + C2b * s10 + C3b * s11;

        acc0 = __builtin_amdgcn_mfma_f32_16x16x32_f16(a0, b00, acc0, 0, 0, 0);
        acc1 = __builtin_amdgcn_mfma_f32_16x16x32_f16(a0, b01, acc1, 0, 0, 0);
        acc2 = __builtin_amdgcn_mfma_f32_16x16x32_f16(a0, b02, acc2, 0, 0, 0);
        acc3 = __builtin_amdgcn_mfma_f32_16x16x32_f16(a0, b03, acc3, 0, 0, 0);
        acc0 = __builtin_amdgcn_mfma_f32_16x16x32_f16(a1, b10, acc0, 0, 0, 0);
        acc1 = __builtin_amdgcn_mfma_f32_16x16x32_f16(a1, b11, acc1, 0, 0, 0);
        acc2 = __builtin_amdgcn_mfma_f32_16x16x32_f16(a1, b12, acc2, 0, 0, 0);
        acc3 = __builtin_amdgcn_mfma_f32_16x16x32_f16(a1, b13, acc3, 0, 0, 0);
    }

    // ---- epilogue: NONTEMPORAL f32x4 stores (lane holds 4 consecutive pixels per o) ----
    {
        int ocol = lane & 15;
        int pixA = wo0 + wl * 16 + khalf * 4;
        float* ob = out + ((size_t)b * COUT) * HW + ho * WW;
        __builtin_nontemporal_store(acc0, (f32x4*)(ob + (size_t)(0 * 16 + ocol) * HW + pixA));
        __builtin_nontemporal_store(acc1, (f32x4*)(ob + (size_t)(1 * 16 + ocol) * HW + pixA));
        __builtin_nontemporal_store(acc2, (f32x4*)(ob + (size_t)(2 * 16 + ocol) * HW + pixA));
        __builtin_nontemporal_store(acc3, (f32x4*)(ob + (size_t)(3 * 16 + ocol) * HW + pixA));
    }
}

extern "C" void kernel_launch(void* const* d_in, const int* in_sizes, int n_in,
                              void* d_out, int out_size, void* d_ws, size_t ws_size,
                              hipStream_t stream)
{
    const float* x    = (const float*)d_in[0];
    const float* woff = (const float*)d_in[1];
    const float* wdef = (const float*)d_in[2];
    float* out  = (float*)d_out;

    unsigned short* wfrag = (unsigned short*)d_ws;          // 73.7 KB
    unsigned short* wfo   = wfrag + 36864;                  // 36.9 KB
    unsigned short* xT    = wfo + 18432;                    // 16.8 MB

    hipLaunchKernelGGL(to_chlast_k, dim3(BATCH * HH), dim3(256), 0, stream,
                       x, xT);
    hipLaunchKernelGGL(build_w_k, dim3((36864 + 18432 + 255) / 256), dim3(256), 0, stream,
                       wdef, woff, wfrag, wfo);
    hipLaunchKernelGGL(deform_fused8_k, dim3((HH / 2) * 2 * 8), dim3(512), 0, stream,
                       xT, (const half8*)wfo, (const half8*)wfrag, out);
}

// Round 22
// 54.804 us; speedup vs baseline: 6.0494x; 1.0012x over previous
//
#include <hip/hip_runtime.h>
#include <hip/hip_bf16.h>

#define BATCH 8
#define CIN   64
#define COUT  64
#define HH    128
#define WW    128
#define HW    (HH * WW)
#define OFFC  18
#define KK    9
#define NROWS 7
#define SPX   36                  // staged columns: 32 + 2 halo each side
#define ROWB2 (SPX * 128)         // 4608 B per staged row

typedef __attribute__((ext_vector_type(8))) _Float16 half8;
typedef __attribute__((ext_vector_type(8))) unsigned short ushort8;
typedef __attribute__((ext_vector_type(4))) float f32x4;

__device__ __forceinline__ unsigned short f2hbits(float v) {
    _Float16 h = (_Float16)v;
    return __builtin_bit_cast(unsigned short, h);
}
__device__ __forceinline__ half8 splat8(float f) {
    _Float16 h = (_Float16)f;
    return (half8){h, h, h, h, h, h, h, h};
}

// ------- Kernel X: x (b,c,h,w) f32 -> xT (b,h,w,c) f16 -------
__global__ __launch_bounds__(256) void to_chlast_k(
    const float* __restrict__ x, unsigned short* __restrict__ xT)
{
    __shared__ unsigned short t[128 * 72];
    int blk = blockIdx.x;                    // ho*8 + b
    int b  = blk & 7;
    int ho = blk >> 3;
    int tid = threadIdx.x;

    const float* xr = x + (size_t)b * CIN * HW + ho * WW;
    for (int i = tid; i < 2048; i += 256) {
        int c = i >> 5, w4 = (i & 31) * 4;
        float4 v = *(const float4*)(xr + (size_t)c * HW + w4);
        t[(w4 + 0) * 72 + c] = f2hbits(v.x);
        t[(w4 + 1) * 72 + c] = f2hbits(v.y);
        t[(w4 + 2) * 72 + c] = f2hbits(v.z);
        t[(w4 + 3) * 72 + c] = f2hbits(v.w);
    }
    __syncthreads();

    unsigned short* orow = xT + (size_t)(b * HH + ho) * WW * 64;
    for (int j = tid; j < 1024; j += 256) {
        int w = j >> 3, c8 = (j & 7) * 8;
        *(ushort8*)(orow + w * 64 + c8) = *(const ushort8*)(t + w * 72 + c8);
    }
}

// ------- Kernel B (merged): w_deform -> wf frags; w_offset -> wfo frags (f16) -------
__global__ __launch_bounds__(256) void build_w_k(
    const float* __restrict__ wd, const float* __restrict__ wo,
    unsigned short* __restrict__ wf, unsigned short* __restrict__ wfo)
{
    int idx = blockIdx.x * 256 + threadIdx.x;
    if (idx < 36864) {                               // wf: o*576 + ck
        int ck = idx % 576;
        int o  = idx / 576;
        int c = ck & 63, k = ck >> 6;
        float v = wd[o * 576 + c * 9 + k];
        int kk = ck >> 5, nt = o >> 4;
        int lane = (o & 15) | (((ck >> 3) & 3) << 4);
        int j = ck & 7;
        wf[((kk * 4 + nt) * 64 + lane) * 8 + j] = f2hbits(v);
    } else if (idx < 36864 + 18432) {                // wfo: ov*576 + ck, N pad 18->32
        int i2 = idx - 36864;
        int ck = i2 % 576;
        int ov = i2 / 576;
        int c = ck & 63, tap = ck >> 6;
        float v = (ov < OFFC) ? wo[ov * 576 + c * 9 + tap] : 0.f;
        int kk = ck >> 5, nt = ov >> 4;
        int lane = (ov & 15) | (((ck >> 3) & 3) << 4);
        int j = ck & 7;
        wfo[((kk * 2 + nt) * 64 + lane) * 8 + j] = f2hbits(v);
    }
}

// ---------- Kernel C: LDS-staged gather, 2-row x 32-px / 256-thr, 4 blocks/CU ----------
// R16 datapath (verified 54.9us) with SMALLER independent blocks for block-level
// de-phasing: stage = 7 rows x 36 cols (+-2 halo) = 32.3KB + offsL 5KB = 37.4KB
// -> 4 blocks/CU at the SAME 4 waves/SIMD. Four independent schedules per CU:
// one block's stage barrier / phase-A MFMA-RAW chain overlaps another's tap loop.
// Grid = 64 rowpairs x 4 wsegs x 8 b = 2048 = exactly 2 full rounds of 4/CU.
// Datapath byte-identical to R16: packed-f16 interp, bit-identical global fallback.
__global__ __launch_bounds__(256, 4) void deform_fusedC_k(
    const unsigned short* __restrict__ xT,
    const half8* __restrict__ wfo,
    const half8* __restrict__ wf, float* __restrict__ out)
{
    __shared__ char  stage[NROWS * ROWB2];  // 32256 B
    __shared__ float offsL[4][16 * 20];     //  5120 B  (total 37376 B)

    int tid  = threadIdx.x;
    int blk  = blockIdx.x;                  // (rp*4+wseg)*8 + b
    int b    = blk & 7;
    int t2   = blk >> 3;
    int wseg = t2 & 3;
    int ho0  = (t2 >> 2) * 2;
    int row_lo = ho0 - 2;                   // staged rows row_lo .. row_lo+6
    int wo0  = wseg * 32;
    int col_lo = wo0 - 2;                   // staged cols col_lo .. col_lo+35

    const unsigned short* pT = xT + (size_t)b * HW * 64;

    int lane  = tid & 63;
    int wave  = tid >> 6;                   // 0..3
    int wl    = wave & 1;                   // px half
    int ho    = ho0 + (wave >> 1);          // this wave's output row
    int prow  = lane & 15;
    int khalf = lane >> 4;
    int px    = wo0 + wl * 16 + prow;       // this lane's pixel (absolute)

    // ---- STAGE: 7 rows x 36 cols of xT[b] -> swizzled LDS (256 threads) ----
    for (int c = tid; c < NROWS * SPX * 8; c += 256) {
        int r    = c / (SPX * 8);
        int rem  = c - r * (SPX * 8);
        int xs   = rem >> 3;
        int slot = rem & 7;
        int ar = row_lo + r, ac = col_lo + xs;
        if ((unsigned)ar < (unsigned)HH && (unsigned)ac < (unsigned)WW) {
            ushort8 v = *(const ushort8*)(pT + (((size_t)ar * WW + ac) << 6) + slot * 8);
            *(ushort8*)(stage + r * ROWB2 + xs * 128 + ((slot ^ (xs & 7)) << 4)) = v;
        }
    }
    __syncthreads();

    auto LRD = [&](int r, int xs, int slot) -> half8 {
        return *(const half8*)(stage + r * ROWB2 + xs * 128 + ((slot ^ (xs & 7)) << 4));
    };
    auto GRD = [&](int idx, int h) -> half8 {
        return *(const half8*)(pT + ((size_t)idx << 6) + (khalf << 3) + h * 32);
    };

    // ---- phase A: offsets conv via MFMA (f16) from the stage ----
    {
        f32x4 oa0 = {0.f,0.f,0.f,0.f}, oa1 = {0.f,0.f,0.f,0.f};
        #pragma unroll
        for (int kk = 0; kk < 18; ++kk) {
            int tap = kk >> 1;
            int y   = ho + tap / 3 - 1;
            int dx  = tap % 3 - 1;
            int slot = khalf + (kk & 1) * 4;
            half8 a0 = {0,0,0,0,0,0,0,0};
            int xw = px + dx;
            if ((unsigned)y < HH && (unsigned)xw < WW) {
                a0 = LRD(y - row_lo, xw - col_lo, slot);   // ry in [1,4], xs in [1,34]
            }
            half8 b0 = wfo[(kk * 2 + 0) * 64 + lane];
            half8 b1 = wfo[(kk * 2 + 1) * 64 + lane];
            oa0 = __builtin_amdgcn_mfma_f32_16x16x32_f16(a0, b0, oa0, 0, 0, 0);
            oa1 = __builtin_amdgcn_mfma_f32_16x16x32_f16(a0, b1, oa1, 0, 0, 0);
        }
        int ocol = lane & 15;
        int pl0  = khalf * 4;
        #pragma unroll
        for (int r = 0; r < 4; ++r)
            offsL[wave][(pl0 + r) * 20 + ocol] = oa0[r];
        if (ocol < 2) {
            #pragma unroll
            for (int r = 0; r < 4; ++r)
                offsL[wave][(pl0 + r) * 20 + 16 + ocol] = oa1[r];
        }
    }
    // no barrier: offsL slice is wave-private

    // ---- tap loop: inline positions + LDS gather + packed-f16 interp + MFMA ----
    f32x4 acc0 = {0.f,0.f,0.f,0.f}, acc1 = {0.f,0.f,0.f,0.f};
    f32x4 acc2 = {0.f,0.f,0.f,0.f}, acc3 = {0.f,0.f,0.f,0.f};

    #pragma unroll
    for (int t = 0; t < 9; ++t) {
        half8 b00 = wf[((2 * t) * 4 + 0) * 64 + lane];
        half8 b01 = wf[((2 * t) * 4 + 1) * 64 + lane];
        half8 b02 = wf[((2 * t) * 4 + 2) * 64 + lane];
        half8 b03 = wf[((2 * t) * 4 + 3) * 64 + lane];
        half8 b10 = wf[((2 * t + 1) * 4 + 0) * 64 + lane];
        half8 b11 = wf[((2 * t + 1) * 4 + 1) * 64 + lane];
        half8 b12 = wf[((2 * t + 1) * 4 + 2) * 64 + lane];
        half8 b13 = wf[((2 * t + 1) * 4 + 3) * 64 + lane];

        // ---------- positions ----------
        float dy = offsL[wave][prow * 20 + 2 * t];
        float dx = offsL[wave][prow * 20 + 2 * t + 1];
        float yy = (float)(ho - 1 + t / 3) + dy;
        float xx = (float)(px - 1 + t % 3) + dx;
        float y0 = floorf(yy), x0 = floorf(xx);
        float wy1 = yy - y0, wx1 = xx - x0;
        float wy0 = 1.f - wy1, wx0 = 1.f - wx1;
        bool vv = (yy > -1.f) && (yy < (float)HH) && (xx > -1.f) && (xx < (float)WW);
        int y0i = (int)y0, x0i = (int)x0;
        bool iy0 = (unsigned)y0i < HH, iy1 = (unsigned)(y0i + 1) < HH;
        bool ix0 = (unsigned)x0i < WW, ix1 = (unsigned)(x0i + 1) < WW;
        float w00 = wy0 * wx0 * ((vv && iy0 && ix0) ? 1.f : 0.f);
        float w01 = wy0 * wx1 * ((vv && iy0 && ix1) ? 1.f : 0.f);
        float w10 = wy1 * wx0 * ((vv && iy1 && ix0) ? 1.f : 0.f);
        float w11 = wy1 * wx1 * ((vv && iy1 && ix1) ? 1.f : 0.f);
        int yc0 = min(max(y0i, 0), HH - 1), yc1 = min(max(y0i + 1, 0), HH - 1);
        int xc0 = min(max(x0i, 0), WW - 1), xc1 = min(max(x0i + 1, 0), WW - 1);

        // ---------- stage coords + in-stage tests ----------
        int ry0 = yc0 - row_lo, ry1 = yc1 - row_lo;
        int xs0 = xc0 - col_lo, xs1 = xc1 - col_lo;
        int r0 = min(max(ry0, 0), NROWS - 1), r1 = min(max(ry1, 0), NROWS - 1);
        int s0 = min(max(xs0, 0), SPX - 1),   s1 = min(max(xs1, 0), SPX - 1);
        bool colOOT = ((unsigned)xs0 >= (unsigned)SPX) || ((unsigned)xs1 >= (unsigned)SPX);
        bool bad0 = ((unsigned)ry0 >= (unsigned)NROWS) || colOOT;
        bool bad1 = ((unsigned)ry1 >= (unsigned)NROWS) || colOOT;

        // ---------- LDS gathers (ds_read_b128) ----------
        half8 C0a = LRD(r0, s0, khalf),     C0b = LRD(r0, s0, khalf + 4);
        half8 C1a = LRD(r0, s1, khalf),     C1b = LRD(r0, s1, khalf + 4);
        half8 C2a = LRD(r1, s0, khalf),     C2b = LRD(r1, s0, khalf + 4);
        half8 C3a = LRD(r1, s1, khalf),     C3b = LRD(r1, s1, khalf + 4);

        // ---------- rare out-of-stage fallbacks (same bytes from global) ----------
        if (bad0) {
            C0a = GRD(yc0 * WW + xc0, 0);  C0b = GRD(yc0 * WW + xc0, 1);
            C1a = GRD(yc0 * WW + xc1, 0);  C1b = GRD(yc0 * WW + xc1, 1);
        }
        if (bad1) {
            C2a = GRD(yc1 * WW + xc0, 0);  C2b = GRD(yc1 * WW + xc0, 1);
            C3a = GRD(yc1 * WW + xc1, 0);  C3b = GRD(yc1 * WW + xc1, 1);
        }

        // ---------- packed-f16 interp: result IS the MFMA fragment ----------
        half8 s00 = splat8(w00), s01 = splat8(w01), s10 = splat8(w10), s11 = splat8(w11);
        half8 a0 = C0a * s00 + C1a * s01 + C2a * s10 + C3a * s11;
        half8 a1 = C0b * s00 + C1b * s01 + C2b * s10 + C3b * s11;

        acc0 = __builtin_amdgcn_mfma_f32_16x16x32_f16(a0, b00, acc0, 0, 0, 0);
        acc1 = __builtin_amdgcn_mfma_f32_16x16x32_f16(a0, b01, acc1, 0, 0, 0);
        acc2 = __builtin_amdgcn_mfma_f32_16x16x32_f16(a0, b02, acc2, 0, 0, 0);
        acc3 = __builtin_amdgcn_mfma_f32_16x16x32_f16(a0, b03, acc3, 0, 0, 0);
        acc0 = __builtin_amdgcn_mfma_f32_16x16x32_f16(a1, b10, acc0, 0, 0, 0);
        acc1 = __builtin_amdgcn_mfma_f32_16x16x32_f16(a1, b11, acc1, 0, 0, 0);
        acc2 = __builtin_amdgcn_mfma_f32_16x16x32_f16(a1, b12, acc2, 0, 0, 0);
        acc3 = __builtin_amdgcn_mfma_f32_16x16x32_f16(a1, b13, acc3, 0, 0, 0);
    }

    // ---- epilogue: NONTEMPORAL f32x4 stores (lane holds 4 consecutive pixels per o) ----
    {
        int ocol = lane & 15;
        int pixA = wo0 + wl * 16 + khalf * 4;
        float* ob = out + ((size_t)b * COUT) * HW + ho * WW;
        __builtin_nontemporal_store(acc0, (f32x4*)(ob + (size_t)(0 * 16 + ocol) * HW + pixA));
        __builtin_nontemporal_store(acc1, (f32x4*)(ob + (size_t)(1 * 16 + ocol) * HW + pixA));
        __builtin_nontemporal_store(acc2, (f32x4*)(ob + (size_t)(2 * 16 + ocol) * HW + pixA));
        __builtin_nontemporal_store(acc3, (f32x4*)(ob + (size_t)(3 * 16 + ocol) * HW + pixA));
    }
}

extern "C" void kernel_launch(void* const* d_in, const int* in_sizes, int n_in,
                              void* d_out, int out_size, void* d_ws, size_t ws_size,
                              hipStream_t stream)
{
    const float* x    = (const float*)d_in[0];
    const float* woff = (const float*)d_in[1];
    const float* wdef = (const float*)d_in[2];
    float* out  = (float*)d_out;

    unsigned short* wfrag = (unsigned short*)d_ws;          // 73.7 KB
    unsigned short* wfo   = wfrag + 36864;                  // 36.9 KB
    unsigned short* xT    = wfo + 18432;                    // 16.8 MB

    hipLaunchKernelGGL(to_chlast_k, dim3(BATCH * HH), dim3(256), 0, stream,
                       x, xT);
    hipLaunchKernelGGL(build_w_k, dim3((36864 + 18432 + 255) / 256), dim3(256), 0, stream,
                       wdef, woff, wfrag, wfo);
    hipLaunchKernelGGL(deform_fusedC_k, dim3((HH / 2) * 4 * 8), dim3(256), 0, stream,
                       xT, (const half8*)wfo, (const half8*)wfrag, out);
}

// Round 23
// 53.545 us; speedup vs baseline: 6.1916x; 1.0235x over previous
//
#include <hip/hip_runtime.h>
#include <hip/hip_bf16.h>

#define BATCH 8
#define CIN   64
#define COUT  64
#define HH    128
#define WW    128
#define HW    (HH * WW)
#define OFFC  18
#define KK    9
#define NROWS 9
#define SPX   36                  // staged columns: 32 + 2 halo each side
#define ROWB2 (SPX * 128)         // 4608 B per staged row

typedef __attribute__((ext_vector_type(8))) _Float16 half8;
typedef __attribute__((ext_vector_type(8))) unsigned short ushort8;
typedef __attribute__((ext_vector_type(4))) float f32x4;

__device__ __forceinline__ unsigned short f2hbits(float v) {
    _Float16 h = (_Float16)v;
    return __builtin_bit_cast(unsigned short, h);
}
__device__ __forceinline__ half8 splat8(float f) {
    _Float16 h = (_Float16)f;
    return (half8){h, h, h, h, h, h, h, h};
}

// ------- Kernel X: x (b,c,h,w) f32 -> xT (b,h,w,c) f16 -------
__global__ __launch_bounds__(256) void to_chlast_k(
    const float* __restrict__ x, unsigned short* __restrict__ xT)
{
    __shared__ unsigned short t[128 * 72];
    int blk = blockIdx.x;                    // ho*8 + b
    int b  = blk & 7;
    int ho = blk >> 3;
    int tid = threadIdx.x;

    const float* xr = x + (size_t)b * CIN * HW + ho * WW;
    for (int i = tid; i < 2048; i += 256) {
        int c = i >> 5, w4 = (i & 31) * 4;
        float4 v = *(const float4*)(xr + (size_t)c * HW + w4);
        t[(w4 + 0) * 72 + c] = f2hbits(v.x);
        t[(w4 + 1) * 72 + c] = f2hbits(v.y);
        t[(w4 + 2) * 72 + c] = f2hbits(v.z);
        t[(w4 + 3) * 72 + c] = f2hbits(v.w);
    }
    __syncthreads();

    unsigned short* orow = xT + (size_t)(b * HH + ho) * WW * 64;
    for (int j = tid; j < 1024; j += 256) {
        int w = j >> 3, c8 = (j & 7) * 8;
        *(ushort8*)(orow + w * 64 + c8) = *(const ushort8*)(t + w * 72 + c8);
    }
}

// ------- Kernel B (merged): w_deform -> wf frags; w_offset -> wfo frags (f16) -------
__global__ __launch_bounds__(256) void build_w_k(
    const float* __restrict__ wd, const float* __restrict__ wo,
    unsigned short* __restrict__ wf, unsigned short* __restrict__ wfo)
{
    int idx = blockIdx.x * 256 + threadIdx.x;
    if (idx < 36864) {                               // wf: o*576 + ck
        int ck = idx % 576;
        int o  = idx / 576;
        int c = ck & 63, k = ck >> 6;
        float v = wd[o * 576 + c * 9 + k];
        int kk = ck >> 5, nt = o >> 4;
        int lane = (o & 15) | (((ck >> 3) & 3) << 4);
        int j = ck & 7;
        wf[((kk * 4 + nt) * 64 + lane) * 8 + j] = f2hbits(v);
    } else if (idx < 36864 + 18432) {                // wfo: ov*576 + ck, N pad 18->32
        int i2 = idx - 36864;
        int ck = i2 % 576;
        int ov = i2 / 576;
        int c = ck & 63, tap = ck >> 6;
        float v = (ov < OFFC) ? wo[ov * 576 + c * 9 + tap] : 0.f;
        int kk = ck >> 5, nt = ov >> 4;
        int lane = (ov & 15) | (((ck >> 3) & 3) << 4);
        int j = ck & 7;
        wfo[((kk * 2 + nt) * 64 + lane) * 8 + j] = f2hbits(v);
    }
}

// ---------- Kernel C: LDS-staged gather, 4-row x 32-px / 512-thr, 3 blocks/CU ----------
// Final TLP test: stage = 9 rows x 36 cols = 41.5KB + offsL 10KB = 51.7KB ->
// 3 blocks/CU -> 6 waves/SIMD (+50% vs R16/R22's 4), and stage redundancy drops
// 3.5 -> 2.25 staged-rows per output row. Datapath byte-identical to the verified
// R16/R22 kernel (packed-f16 interp, pre-masked weights, bit-identical fallback).
// 8 waves: wave w -> row ho0+(w>>1), px-half w&1 (16 px each).
__global__ __launch_bounds__(512, 4) void deform_fusedD_k(
    const unsigned short* __restrict__ xT,
    const half8* __restrict__ wfo,
    const half8* __restrict__ wf, float* __restrict__ out)
{
    __shared__ char  stage[NROWS * ROWB2];  // 41472 B
    __shared__ float offsL[8][16 * 20];     // 10240 B  (total 51712 B)

    int tid  = threadIdx.x;
    int blk  = blockIdx.x;                  // (quad*4+wseg)*8 + b
    int b    = blk & 7;
    int t2   = blk >> 3;
    int wseg = t2 & 3;
    int ho0  = (t2 >> 2) * 4;               // 4 rows per block
    int row_lo = ho0 - 2;                   // staged rows row_lo .. row_lo+8
    int wo0  = wseg * 32;
    int col_lo = wo0 - 2;                   // staged cols col_lo .. col_lo+35

    const unsigned short* pT = xT + (size_t)b * HW * 64;

    int lane  = tid & 63;
    int wave  = tid >> 6;                   // 0..7
    int wl    = wave & 1;                   // px half
    int ho    = ho0 + (wave >> 1);          // this wave's output row (4 rows x 2 halves)
    int prow  = lane & 15;
    int khalf = lane >> 4;
    int px    = wo0 + wl * 16 + prow;       // this lane's pixel (absolute)

    // ---- STAGE: 9 rows x 36 cols of xT[b] -> swizzled LDS (512 threads) ----
    for (int c = tid; c < NROWS * SPX * 8; c += 512) {
        int r    = c / (SPX * 8);
        int rem  = c - r * (SPX * 8);
        int xs   = rem >> 3;
        int slot = rem & 7;
        int ar = row_lo + r, ac = col_lo + xs;
        if ((unsigned)ar < (unsigned)HH && (unsigned)ac < (unsigned)WW) {
            ushort8 v = *(const ushort8*)(pT + (((size_t)ar * WW + ac) << 6) + slot * 8);
            *(ushort8*)(stage + r * ROWB2 + xs * 128 + ((slot ^ (xs & 7)) << 4)) = v;
        }
    }
    __syncthreads();

    auto LRD = [&](int r, int xs, int slot) -> half8 {
        return *(const half8*)(stage + r * ROWB2 + xs * 128 + ((slot ^ (xs & 7)) << 4));
    };
    auto GRD = [&](int idx, int h) -> half8 {
        return *(const half8*)(pT + ((size_t)idx << 6) + (khalf << 3) + h * 32);
    };

    // ---- phase A: offsets conv via MFMA (f16) from the stage ----
    {
        f32x4 oa0 = {0.f,0.f,0.f,0.f}, oa1 = {0.f,0.f,0.f,0.f};
        #pragma unroll
        for (int kk = 0; kk < 18; ++kk) {
            int tap = kk >> 1;
            int y   = ho + tap / 3 - 1;            // in [ho0-1, ho0+4], always staged
            int dx  = tap % 3 - 1;
            int slot = khalf + (kk & 1) * 4;
            half8 a0 = {0,0,0,0,0,0,0,0};
            int xw = px + dx;
            if ((unsigned)y < HH && (unsigned)xw < WW) {
                a0 = LRD(y - row_lo, xw - col_lo, slot);   // ry in [1,6], xs in [1,34]
            }
            half8 b0 = wfo[(kk * 2 + 0) * 64 + lane];
            half8 b1 = wfo[(kk * 2 + 1) * 64 + lane];
            oa0 = __builtin_amdgcn_mfma_f32_16x16x32_f16(a0, b0, oa0, 0, 0, 0);
            oa1 = __builtin_amdgcn_mfma_f32_16x16x32_f16(a0, b1, oa1, 0, 0, 0);
        }
        int ocol = lane & 15;
        int pl0  = khalf * 4;
        #pragma unroll
        for (int r = 0; r < 4; ++r)
            offsL[wave][(pl0 + r) * 20 + ocol] = oa0[r];
        if (ocol < 2) {
            #pragma unroll
            for (int r = 0; r < 4; ++r)
                offsL[wave][(pl0 + r) * 20 + 16 + ocol] = oa1[r];
        }
    }
    // no barrier: offsL slice is wave-private

    // ---- tap loop: inline positions + LDS gather + packed-f16 interp + MFMA ----
    f32x4 acc0 = {0.f,0.f,0.f,0.f}, acc1 = {0.f,0.f,0.f,0.f};
    f32x4 acc2 = {0.f,0.f,0.f,0.f}, acc3 = {0.f,0.f,0.f,0.f};

    #pragma unroll
    for (int t = 0; t < 9; ++t) {
        half8 b00 = wf[((2 * t) * 4 + 0) * 64 + lane];
        half8 b01 = wf[((2 * t) * 4 + 1) * 64 + lane];
        half8 b02 = wf[((2 * t) * 4 + 2) * 64 + lane];
        half8 b03 = wf[((2 * t) * 4 + 3) * 64 + lane];
        half8 b10 = wf[((2 * t + 1) * 4 + 0) * 64 + lane];
        half8 b11 = wf[((2 * t + 1) * 4 + 1) * 64 + lane];
        half8 b12 = wf[((2 * t + 1) * 4 + 2) * 64 + lane];
        half8 b13 = wf[((2 * t + 1) * 4 + 3) * 64 + lane];

        // ---------- positions ----------
        float dy = offsL[wave][prow * 20 + 2 * t];
        float dx = offsL[wave][prow * 20 + 2 * t + 1];
        float yy = (float)(ho - 1 + t / 3) + dy;
        float xx = (float)(px - 1 + t % 3) + dx;
        float y0 = floorf(yy), x0 = floorf(xx);
        float wy1 = yy - y0, wx1 = xx - x0;
        float wy0 = 1.f - wy1, wx0 = 1.f - wx1;
        bool vv = (yy > -1.f) && (yy < (float)HH) && (xx > -1.f) && (xx < (float)WW);
        int y0i = (int)y0, x0i = (int)x0;
        bool iy0 = (unsigned)y0i < HH, iy1 = (unsigned)(y0i + 1) < HH;
        bool ix0 = (unsigned)x0i < WW, ix1 = (unsigned)(x0i + 1) < WW;
        float w00 = wy0 * wx0 * ((vv && iy0 && ix0) ? 1.f : 0.f);
        float w01 = wy0 * wx1 * ((vv && iy0 && ix1) ? 1.f : 0.f);
        float w10 = wy1 * wx0 * ((vv && iy1 && ix0) ? 1.f : 0.f);
        float w11 = wy1 * wx1 * ((vv && iy1 && ix1) ? 1.f : 0.f);
        int yc0 = min(max(y0i, 0), HH - 1), yc1 = min(max(y0i + 1, 0), HH - 1);
        int xc0 = min(max(x0i, 0), WW - 1), xc1 = min(max(x0i + 1, 0), WW - 1);

        // ---------- stage coords + in-stage tests ----------
        int ry0 = yc0 - row_lo, ry1 = yc1 - row_lo;
        int xs0 = xc0 - col_lo, xs1 = xc1 - col_lo;
        int r0 = min(max(ry0, 0), NROWS - 1), r1 = min(max(ry1, 0), NROWS - 1);
        int s0 = min(max(xs0, 0), SPX - 1),   s1 = min(max(xs1, 0), SPX - 1);
        bool colOOT = ((unsigned)xs0 >= (unsigned)SPX) || ((unsigned)xs1 >= (unsigned)SPX);
        bool bad0 = ((unsigned)ry0 >= (unsigned)NROWS) || colOOT;
        bool bad1 = ((unsigned)ry1 >= (unsigned)NROWS) || colOOT;

        // ---------- LDS gathers (ds_read_b128) ----------
        half8 C0a = LRD(r0, s0, khalf),     C0b = LRD(r0, s0, khalf + 4);
        half8 C1a = LRD(r0, s1, khalf),     C1b = LRD(r0, s1, khalf + 4);
        half8 C2a = LRD(r1, s0, khalf),     C2b = LRD(r1, s0, khalf + 4);
        half8 C3a = LRD(r1, s1, khalf),     C3b = LRD(r1, s1, khalf + 4);

        // ---------- rare out-of-stage fallbacks (same bytes from global) ----------
        if (bad0) {
            C0a = GRD(yc0 * WW + xc0, 0);  C0b = GRD(yc0 * WW + xc0, 1);
            C1a = GRD(yc0 * WW + xc1, 0);  C1b = GRD(yc0 * WW + xc1, 1);
        }
        if (bad1) {
            C2a = GRD(yc1 * WW + xc0, 0);  C2b = GRD(yc1 * WW + xc0, 1);
            C3a = GRD(yc1 * WW + xc1, 0);  C3b = GRD(yc1 * WW + xc1, 1);
        }

        // ---------- packed-f16 interp: result IS the MFMA fragment ----------
        half8 s00 = splat8(w00), s01 = splat8(w01), s10 = splat8(w10), s11 = splat8(w11);
        half8 a0 = C0a * s00 + C1a * s01 + C2a * s10 + C3a * s11;
        half8 a1 = C0b * s00 + C1b * s01 + C2b * s10 + C3b * s11;

        acc0 = __builtin_amdgcn_mfma_f32_16x16x32_f16(a0, b00, acc0, 0, 0, 0);
        acc1 = __builtin_amdgcn_mfma_f32_16x16x32_f16(a0, b01, acc1, 0, 0, 0);
        acc2 = __builtin_amdgcn_mfma_f32_16x16x32_f16(a0, b02, acc2, 0, 0, 0);
        acc3 = __builtin_amdgcn_mfma_f32_16x16x32_f16(a0, b03, acc3, 0, 0, 0);
        acc0 = __builtin_amdgcn_mfma_f32_16x16x32_f16(a1, b10, acc0, 0, 0, 0);
        acc1 = __builtin_amdgcn_mfma_f32_16x16x32_f16(a1, b11, acc1, 0, 0, 0);
        acc2 = __builtin_amdgcn_mfma_f32_16x16x32_f16(a1, b12, acc2, 0, 0, 0);
        acc3 = __builtin_amdgcn_mfma_f32_16x16x32_f16(a1, b13, acc3, 0, 0, 0);
    }

    // ---- epilogue: NONTEMPORAL f32x4 stores (lane holds 4 consecutive pixels per o) ----
    {
        int ocol = lane & 15;
        int pixA = wo0 + wl * 16 + khalf * 4;
        float* ob = out + ((size_t)b * COUT) * HW + ho * WW;
        __builtin_nontemporal_store(acc0, (f32x4*)(ob + (size_t)(0 * 16 + ocol) * HW + pixA));
        __builtin_nontemporal_store(acc1, (f32x4*)(ob + (size_t)(1 * 16 + ocol) * HW + pixA));
        __builtin_nontemporal_store(acc2, (f32x4*)(ob + (size_t)(2 * 16 + ocol) * HW + pixA));
        __builtin_nontemporal_store(acc3, (f32x4*)(ob + (size_t)(3 * 16 + ocol) * HW + pixA));
    }
}

extern "C" void kernel_launch(void* const* d_in, const int* in_sizes, int n_in,
                              void* d_out, int out_size, void* d_ws, size_t ws_size,
                              hipStream_t stream)
{
    const float* x    = (const float*)d_in[0];
    const float* woff = (const float*)d_in[1];
    const float* wdef = (const float*)d_in[2];
    float* out  = (float*)d_out;

    unsigned short* wfrag = (unsigned short*)d_ws;          // 73.7 KB
    unsigned short* wfo   = wfrag + 36864;                  // 36.9 KB
    unsigned short* xT    = wfo + 18432;                    // 16.8 MB

    hipLaunchKernelGGL(to_chlast_k, dim3(BATCH * HH), dim3(256), 0, stream,
                       x, xT);
    hipLaunchKernelGGL(build_w_k, dim3((36864 + 18432 + 255) / 256), dim3(256), 0, stream,
                       wdef, woff, wfrag, wfo);
    hipLaunchKernelGGL(deform_fusedD_k, dim3((HH / 4) * 4 * 8), dim3(512), 0, stream,
                       xT, (const half8*)wfo, (const half8*)wfrag, out);
}